// Round 16
// baseline (3013.180 us; speedup 1.0000x reference)
//
#include <hip/hip_runtime.h>

typedef __attribute__((ext_vector_type(8))) short short8;
typedef __attribute__((ext_vector_type(4))) float f32x4;
typedef __attribute__((ext_vector_type(4))) _Float16 f16x4;
typedef __attribute__((ext_vector_type(4))) unsigned int u32x4;
typedef unsigned long long u64_t;

#define DI __device__ __forceinline__

// ---------------- helpers ----------------
DI unsigned short f2bf(float f) {            // RNE float->bf16
  unsigned int u = __float_as_uint(f);
  u += 0x7FFFu + ((u >> 16) & 1u);
  return (unsigned short)(u >> 16);
}

DI void gload_lds16(const void* g, void* l) { // async global->LDS, 16B/lane
  __builtin_amdgcn_global_load_lds(
      (const __attribute__((address_space(1))) unsigned int*)g,
      (__attribute__((address_space(3))) unsigned int*)l, 16, 0, 0);
}

DI float sigm(float x) { return 1.f / (1.f + __expf(-x)); }
DI float tanh_(float x) { return 1.f - 2.f / (__expf(2.f * x) + 1.f); }

// LLC-coherent 16B load (sc0 sc1) — correctness-proven in the R12 stage role
DI u32x4 h_load16(const void* p) {  // no waitcnt: caller drains once
  u32x4 r;
  asm volatile("global_load_dwordx4 %0, %1, off sc0 sc1" : "=v"(r) : "v"(p) : "memory");
  return r;
}

// ---------------- sizes / workspace layout ----------------
// B=64 C=800 T=512 H=1024 IN=1600 4H=4096 TB=32768
// colp = hcol*4 + gate  (gate f,i,u,o = 0..3) — used by gx, Wxt, Wht packing.
static constexpr size_t OFF_WXT  = 0;                       // bf16 [4096][1600] colp-major
static constexpr size_t OFF_WHT  = 13107200;                // bf16 [4096][1024] colp-major
static constexpr size_t OFF_BSUM = OFF_WHT + 8388608;       // f32  [4096] (bx+bh, plain col)
static constexpr size_t OFF_XS   = OFF_BSUM + 16384;        // u32  [32768][800] (bf16 x,y interleaved)
static constexpr size_t OFF_GX   = OFF_XS + 104857600;      // f16  [32768][4096] (colp)
static constexpr size_t OFF_HBUF = OFF_GX + 268435456;      // u32  8 grp x 2 buf x [8][512]
static constexpr size_t OFF_BAR  = OFF_HBUF + 262144;       // u32  256 x 32-stride flags (32 KB)
static constexpr size_t WS_NEED  = OFF_BAR + 32768;

// ---------------- K1: pack gate weights, transposed, to bf16 ----------------
// perm=0: dst[n][k], n = gate*1024+col;  perm=1: dst[colp][k], colp = col*4+gate
__global__ __launch_bounds__(256) void pack_w(
    const float* __restrict__ s0, const float* __restrict__ s1,
    const float* __restrict__ s2, const float* __restrict__ s3,
    unsigned short* __restrict__ dst, int K, int perm) {
  __shared__ float tile[32][33];
  const int tx = threadIdx.x & 31, ty = threadIdx.x >> 5;
  const int kt = blockIdx.x, nt = blockIdx.y;
  const int q = (nt * 32) >> 10;
  const float* src = (q == 0) ? s0 : (q == 1) ? s1 : (q == 2) ? s2 : s3;
  const int cbase = (nt * 32) & 1023;
#pragma unroll
  for (int i = 0; i < 4; ++i) {
    int k = kt * 32 + ty + i * 8;
    tile[ty + i * 8][tx] = src[(size_t)k * 1024 + cbase + tx];
  }
  __syncthreads();
#pragma unroll
  for (int i = 0; i < 4; ++i) {
    int n = nt * 32 + ty + i * 8;
    int np = perm ? ((n & 1023) * 4 + (n >> 10)) : n;
    dst[(size_t)np * K + kt * 32 + tx] = f2bf(tile[tx][ty + i * 8]);
  }
}

// ---------------- K2: combined bias bx+bh ----------------
__global__ __launch_bounds__(256) void pack_bias(
    const float* bx0, const float* bx1, const float* bx2, const float* bx3,
    const float* bh0, const float* bh1, const float* bh2, const float* bh3,
    float* __restrict__ bsum) {
  int n = blockIdx.x * 256 + threadIdx.x;
  int q = n >> 10, j = n & 1023;
  const float* bx = (q == 0) ? bx0 : (q == 1) ? bx1 : (q == 2) ? bx2 : bx3;
  const float* bh = (q == 0) ? bh0 : (q == 1) ? bh1 : (q == 2) ? bh2 : bh3;
  bsum[n] = bx[j] + bh[j];
}

// ---------------- K3: build xs bf16 [T*B][1600] ----------------
__global__ __launch_bounds__(256) void xs_pack(
    const float* __restrict__ x, const float* __restrict__ y,
    unsigned int* __restrict__ xs32) {
  __shared__ float xt[32][33], yt[32][33];
  const int tx = threadIdx.x & 31, ty = threadIdx.x >> 5;
  const int tt = blockIdx.x, ct = blockIdx.y, b = blockIdx.z;
#pragma unroll
  for (int i = 0; i < 4; ++i) {
    int c = ct * 32 + ty + i * 8;
    int t = tt * 32 + tx;
    size_t base = ((size_t)b * 800 + c) * 512;
    xt[ty + i * 8][tx] = x[base + t];
    yt[ty + i * 8][tx] = (t == 0) ? 0.f : y[base + t - 1];
  }
  __syncthreads();
#pragma unroll
  for (int i = 0; i < 4; ++i) {
    int t = tt * 32 + ty + i * 8;
    int c = ct * 32 + tx;
    unsigned int pk = ((unsigned int)f2bf(yt[tx][ty + i * 8]) << 16) |
                      (unsigned int)f2bf(xt[tx][ty + i * 8]);
    xs32[((size_t)t * 64 + b) * 800 + c] = pk;
  }
}

// ---------------- K4: gx GEMM — 256x256 tile, BK=32, 3-slot pipeline --------
// B operand = Wxt in colp-major -> block's output cols are CONTIGUOUS in gx
// (epilogue stores sequential 32B chunks instead of stride-8B f16 scatter).
// Bias decoded per colp. Pipeline identical to R15 (counted vmcnt(8)).
__global__ __launch_bounds__(512, 2) void gemm_gx(
    const unsigned short* __restrict__ xs, const unsigned short* __restrict__ Wxtp,
    const float* __restrict__ bsum, _Float16* __restrict__ gx) {
  __shared__ __align__(16) char smem[98304];  // A: 3x16KB @0, B: 3x16KB @49152
  const int tid = threadIdx.x;
  const int w = tid >> 6, l = tid & 63;
  const int l15 = l & 15, l4 = l >> 4;
  const int wm = w >> 2, wn = w & 3;
  // XCD-aware bijective swizzle (2048 % 8 == 0)
  const int u = (blockIdx.x & 7) * 256 + (blockIdx.x >> 3);
  const int bm = u >> 4, bn = u & 15;

  const unsigned short* abase0 = xs + (size_t)(bm * 256) * 1600;
  const unsigned short* bbase0 = Wxtp + (size_t)(bn * 256) * 1600;

  // staging geometry: tile-operand = 1024 chunks of 16B ([256 rows][4 kc])
  const int c0 = w * 64 + l;
  const int r0 = c0 >> 2, k0 = c0 & 3;
  const int c1 = 512 + c0;
  const int r1 = c1 >> 2, k1 = c1 & 3;
  const int dst0 = w * 1024;
  const int dst1 = 8192 + w * 1024;

#define STAGE(kt2, slot)                                                        \
  {                                                                             \
    const unsigned short* ab = abase0 + (kt2) * 32;                             \
    const unsigned short* bb = bbase0 + (kt2) * 32;                             \
    char* Asl = smem + (slot) * 16384;                                          \
    char* Bsl = smem + 49152 + (slot) * 16384;                                  \
    gload_lds16(ab + (size_t)r0 * 1600 + k0 * 8, Asl + dst0);                   \
    gload_lds16(bb + (size_t)r0 * 1600 + k0 * 8, Bsl + dst0);                   \
    gload_lds16(ab + (size_t)r1 * 1600 + k1 * 8, Asl + dst1);                   \
    gload_lds16(bb + (size_t)r1 * 1600 + k1 * 8, Bsl + dst1);                   \
  }

  f32x4 acc[8][4];
#pragma unroll
  for (int i = 0; i < 8; ++i)
#pragma unroll
    for (int j = 0; j < 4; ++j) acc[i][j] = (f32x4){0.f, 0.f, 0.f, 0.f};

  STAGE(0, 0);
  STAGE(1, 1);
  STAGE(2, 2);

  int slot = 0;
  for (int t = 0; t < 50; ++t) {
    if (t < 48) {
      asm volatile("s_waitcnt vmcnt(8)" ::: "memory");
    } else {
      asm volatile("s_waitcnt vmcnt(0)" ::: "memory");
    }
    __builtin_amdgcn_s_barrier();
    const char* Asl = smem + slot * 16384;
    const char* Bsl = smem + 49152 + slot * 16384;
    short8 af[8], bf[4];
#pragma unroll
    for (int mf = 0; mf < 8; ++mf)
      af[mf] = *(const short8*)(Asl + (wm * 128 + mf * 16 + l15) * 64 + l4 * 16);
#pragma unroll
    for (int nf = 0; nf < 4; ++nf)
      bf[nf] = *(const short8*)(Bsl + (wn * 64 + nf * 16 + l15) * 64 + l4 * 16);
    __builtin_amdgcn_s_setprio(1);
#pragma unroll
    for (int mf = 0; mf < 8; ++mf)
#pragma unroll
      for (int nf = 0; nf < 4; ++nf)
        acc[mf][nf] = __builtin_amdgcn_mfma_f32_16x16x32_bf16(
            af[mf], bf[nf], acc[mf][nf], 0, 0, 0);
    __builtin_amdgcn_s_setprio(0);
    __builtin_amdgcn_s_barrier();
    asm volatile("" ::: "memory");
    if (t + 3 < 50) STAGE(t + 3, slot);
    slot = (slot == 2) ? 0 : slot + 1;
  }
#undef STAGE

  // epilogue: + bias, store f16 at contiguous colp
#pragma unroll
  for (int nf = 0; nf < 4; ++nf) {
    int colp = bn * 256 + wn * 64 + nf * 16 + l15;
    float bs = bsum[(colp & 3) * 1024 + (colp >> 2)];
#pragma unroll
    for (int mf = 0; mf < 8; ++mf) {
      int row0 = bm * 256 + wm * 128 + mf * 16 + l4 * 4;
#pragma unroll
      for (int j = 0; j < 4; ++j)
        gx[(size_t)(row0 + j) * 4096 + colp] = (_Float16)(acc[mf][nf][j] + bs);
    }
  }
}

// ---------------- K5: persistent LSTM recurrence (no K-split, colp waves) ---
// 8 groups (gg=blockIdx&7) x 32 WGs (cwg), 512 thr, 96KB LDS -> 1 WG/CU.
// Wave w owns gate-cols colp = cwg*128 + w*16 + l15 (= 4 h-cols x 4 gates,
// quad-aligned), FULL K=1024 in regs (Bf[32], 128 VGPR). Per step:
//   wave7 relay-polls the 32 per-WG flags (own 128B lines) -> syncA ->
//   batched cooperative 16KB h stage (2 x dwordx4 sc0sc1, one vmcnt(0),
//   2 swizzled 16B ds_writes) -> per-lane gx scalar loads -> syncB ->
//   32 MFMAs (2 chains, full K) -> ALL waves finalize in parallel: in-quad
//   gate shuffles, c/h update, paired h-store -> vmcnt(0) -> syncD -> tid0
//   stores single per-WG flag. 3 barriers/step (syncC + partials removed).
__global__ __launch_bounds__(512, 2) void lstm_seq(
    const _Float16* __restrict__ gx, const unsigned short* __restrict__ Whtp,
    const float* __restrict__ subj, const float* __restrict__ Winit,
    const float* __restrict__ binit, float* __restrict__ out,
    unsigned int* __restrict__ hbuf, unsigned int* __restrict__ bar) {
  const int gg  = blockIdx.x & 7;
  const int cwg = blockIdx.x >> 3;
  const int tid = threadIdx.x;
  const int w = tid >> 6, l = tid & 63;
  const int l15 = l & 15, l4 = l >> 4;
  const int ghc = cwg * 32 + w * 4 + (l15 >> 2);  // this lane's h-col
  const int colp = cwg * 128 + w * 16 + l15;      // this lane's gate-col

  __shared__ __align__(16) char smem[98304];  // 96 KB -> exclusive CU (16KB used)

  // Wh B-fragments: full K=1024 for this lane's gate-col (128 VGPR)
  short8 Bf[32];
  {
    const unsigned short* wp = Whtp + (size_t)colp * 1024 + l4 * 8;
#pragma unroll
    for (int kk = 0; kk < 32; ++kk) Bf[kk] = *(const short8*)(wp + kk * 32);
  }

  // c0 = subject_id @ W_init + b_init (lanes l4<2; quad lanes replicate)
  float c[4], hq[4][8];
  if (l4 < 2) {
#pragma unroll
    for (int j = 0; j < 4; ++j) {
      int b = gg * 8 + l4 * 4 + j;
      float a = binit[ghc];
      for (int k = 0; k < 87; ++k) a += subj[b * 87 + k] * Winit[k * 1024 + ghc];
      c[j] = a;
    }
  }

  unsigned int* flags = bar + gg * 1024;  // 32 WGs x 32-u32 stride (128B/line)

  // batched stage addressing: 16B chunks tid and tid+512 (1024 total = 16KB)
  const int so0 = tid * 16;
  const int so1 = (tid + 512) * 16;
  const int sw0 = so0 ^ (((so0 >> 11) & 7) << 4);
  const int sw1 = so1 ^ (((so1 >> 11) & 7) << 4);

  for (int t8 = 0; t8 < 64; ++t8) {
#pragma unroll
    for (int s = 0; s < 8; ++s) {
      const int t = t8 * 8 + s;
      const int cur = s & 1, nxt = cur ^ 1;
      // 1. poll: wave 7's 32 lanes read the 32 WG flags (distinct lines)
      if (w == 7) {
        const unsigned tgt = (unsigned)t;
        for (;;) {
          unsigned f = 0xFFFFFFFFu;
          if (l < 32)
            f = __hip_atomic_load(flags + l * 32, __ATOMIC_RELAXED,
                                  __HIP_MEMORY_SCOPE_AGENT);
          if (__all(f >= tgt)) break;
          __builtin_amdgcn_s_sleep(1);
        }
      }
      __syncthreads();  // A: h(t) visible to all
      // 2. batched cooperative stage: 2 x 16B loads, one drain, swizzled writes
      {
        const char* src = (const char*)hbuf + (size_t)(gg * 2 + cur) * 16384;
        u32x4 v0 = h_load16(src + so0);
        u32x4 v1 = h_load16(src + so1);
        asm volatile("s_waitcnt vmcnt(0)" ::: "memory");
        *(u32x4*)(smem + sw0) = v0;
        *(u32x4*)(smem + sw1) = v1;
      }
      // 3. gx scalar loads (per-lane gate value; consumed after MFMA)
      float gxv[4];
      if (l4 < 2) {
        const _Float16* gp = gx + ((size_t)(t * 64 + gg * 8 + l4 * 4)) * 4096 + colp;
#pragma unroll
        for (int j = 0; j < 4; ++j) gxv[j] = (float)gp[(size_t)j * 4096];
      }
      __syncthreads();  // B: staged h readable
      // 4. MFMA: 32 over full K, 2 independent chains
      f32x4 a0 = {0.f, 0.f, 0.f, 0.f}, a1 = {0.f, 0.f, 0.f, 0.f};
#pragma unroll
      for (int kk = 0; kk < 32; kk += 2) {
        short8 v0 = *(const short8*)(
            smem + (((l15 & 7) * 2048 + kk * 64 + l4 * 16) ^ ((l15 & 7) << 4)));
        a0 = __builtin_amdgcn_mfma_f32_16x16x32_bf16(v0, Bf[kk], a0, 0, 0, 0);
        short8 v1 = *(const short8*)(
            smem + (((l15 & 7) * 2048 + (kk + 1) * 64 + l4 * 16) ^ ((l15 & 7) << 4)));
        a1 = __builtin_amdgcn_mfma_f32_16x16x32_bf16(v1, Bf[kk + 1], a1, 0, 0, 0);
      }
      f32x4 acc = a0 + a1;
      // 5. finalize: ALL waves, in-quad gate shuffles (f,i,u,o at l&~3..+3)
      if (l4 < 2) {
#pragma unroll
        for (int j = 0; j < 4; ++j) {
          float g = acc[j] + gxv[j];
          int base = l & ~3;
          float fv = sigm(__shfl(g, base));
          float iv = sigm(__shfl(g, base + 1));
          float uv = tanh_(__shfl(g, base + 2));
          float ov = sigm(__shfl(g, base + 3));
          c[j] = c[j] * fv + iv * uv;
          float hv = ov * tanh_(c[j]);
          hq[j][s] = hv;
          float hn = __shfl(hv, l ^ 4);  // neighbor h-col (quad-pair) value
          if ((l15 & 7) == 0) {          // writers: l15 in {0,8}
            unsigned int pk = (unsigned int)f2bf(hv) | ((unsigned int)f2bf(hn) << 16);
            __hip_atomic_store(
                hbuf + (gg * 2 + nxt) * 4096 + (l4 * 4 + j) * 512 +
                    cwg * 16 + w * 2 + (l15 >> 3),
                pk, __ATOMIC_RELAXED, __HIP_MEMORY_SCOPE_AGENT);
          }
        }
      }
      asm volatile("s_waitcnt vmcnt(0)" ::: "memory");  // drain h-stores
      __syncthreads();  // D: all waves drained
      if (tid == 0)
        __hip_atomic_store(flags + cwg * 32, (unsigned)(t + 1),
                           __ATOMIC_RELAXED, __HIP_MEMORY_SCOPE_AGENT);
    }
    // flush 8-step h_seq window (32B chunks; one writer per (row, h-col))
    if (l4 < 2 && (l15 & 3) == 0) {
      int tb = t8 * 8;
#pragma unroll
      for (int j = 0; j < 4; ++j) {
        f32x4 v0 = {hq[j][0], hq[j][1], hq[j][2], hq[j][3]};
        f32x4 v1 = {hq[j][4], hq[j][5], hq[j][6], hq[j][7]};
        float* op = out + (size_t)(gg * 8 + l4 * 4 + j) * 524288 + (size_t)ghc * 512 + tb;
        *(f32x4*)op = v0;
        *(f32x4*)(op + 4) = v1;
      }
    }
  }
  if (l4 < 2 && (l15 & 3) == 0) {  // c_fin
#pragma unroll
    for (int j = 0; j < 4; ++j)
      out[33554432 + (size_t)(gg * 8 + l4 * 4 + j) * 1024 + ghc] = c[j];
  }
}

// ---------------- launch ----------------
extern "C" void kernel_launch(void* const* d_in, const int* in_sizes, int n_in,
                              void* d_out, int out_size, void* d_ws, size_t ws_size,
                              hipStream_t stream) {
  (void)in_sizes; (void)n_in; (void)out_size;
  if (ws_size < WS_NEED) return;

  const float* x     = (const float*)d_in[0];
  const float* y     = (const float*)d_in[1];
  const float* subj  = (const float*)d_in[2];
  const float* W_fx  = (const float*)d_in[3];
  const float* b_fx  = (const float*)d_in[4];
  const float* W_fh  = (const float*)d_in[5];
  const float* b_fh  = (const float*)d_in[6];
  const float* W_ix  = (const float*)d_in[7];
  const float* b_ix  = (const float*)d_in[8];
  const float* W_ih  = (const float*)d_in[9];
  const float* b_ih  = (const float*)d_in[10];
  const float* W_ux  = (const float*)d_in[11];
  const float* b_ux  = (const float*)d_in[12];
  const float* W_uh  = (const float*)d_in[13];
  const float* b_uh  = (const float*)d_in[14];
  const float* W_ox  = (const float*)d_in[15];
  const float* b_ox  = (const float*)d_in[16];
  const float* W_oh  = (const float*)d_in[17];
  const float* b_oh  = (const float*)d_in[18];
  const float* Winit = (const float*)d_in[19];
  const float* binit = (const float*)d_in[20];
  float* out = (float*)d_out;

  char* ws = (char*)d_ws;
  unsigned short* Wxt  = (unsigned short*)(ws + OFF_WXT);
  unsigned short* Wht  = (unsigned short*)(ws + OFF_WHT);
  float*          bsum = (float*)(ws + OFF_BSUM);
  unsigned int*   xs32 = (unsigned int*)(ws + OFF_XS);
  _Float16*       gx   = (_Float16*)(ws + OFF_GX);
  unsigned int*   hbuf = (unsigned int*)(ws + OFF_HBUF);
  unsigned int*   bar  = (unsigned int*)(ws + OFF_BAR);

  // deterministic per-call init: h(0)=0 in both buffers, flags=0
  hipMemsetAsync(ws + OFF_HBUF, 0, WS_NEED - OFF_HBUF, stream);

  pack_w<<<dim3(50, 128), 256, 0, stream>>>(W_fx, W_ix, W_ux, W_ox, Wxt, 1600, 1);
  pack_w<<<dim3(32, 128), 256, 0, stream>>>(W_fh, W_ih, W_uh, W_oh, Wht, 1024, 1);
  pack_bias<<<16, 256, 0, stream>>>(b_fx, b_ix, b_ux, b_ox, b_fh, b_ih, b_uh, b_oh, bsum);
  xs_pack<<<dim3(16, 25, 64), 256, 0, stream>>>(x, y, xs32);
  gemm_gx<<<2048, 512, 0, stream>>>((const unsigned short*)xs32, Wxt, bsum, gx);

  const _Float16* gxc = gx;
  const unsigned short* whtc = Wht;
  void* ka[8] = {(void*)&gxc, (void*)&whtc, (void*)&subj, (void*)&Winit,
                 (void*)&binit, (void*)&out, (void*)&hbuf, (void*)&bar};
  hipError_t e = hipLaunchCooperativeKernel((const void*)lstm_seq, dim3(256), dim3(512),
                                            ka, 0, stream);
  if (e != hipSuccess) {
    // fallback: plain launch; 256 WGs at 1 WG/CU (96KB LDS) co-resident on 256 CUs
    lstm_seq<<<256, 512, 0, stream>>>(gxc, whtc, subj, Winit, binit, out, hbuf, bar);
  }
}

// Round 17
// 2682.657 us; speedup vs baseline: 1.1232x; 1.1232x over previous
//
#include <hip/hip_runtime.h>

typedef __attribute__((ext_vector_type(8))) short short8;
typedef __attribute__((ext_vector_type(4))) float f32x4;
typedef __attribute__((ext_vector_type(4))) _Float16 f16x4;
typedef __attribute__((ext_vector_type(4))) unsigned int u32x4;
typedef unsigned long long u64_t;

#define DI __device__ __forceinline__

// ---------------- helpers ----------------
DI unsigned short f2bf(float f) {            // RNE float->bf16
  unsigned int u = __float_as_uint(f);
  u += 0x7FFFu + ((u >> 16) & 1u);
  return (unsigned short)(u >> 16);
}

DI void gload_lds16(const void* g, void* l) { // async global->LDS, 16B/lane
  __builtin_amdgcn_global_load_lds(
      (const __attribute__((address_space(1))) unsigned int*)g,
      (__attribute__((address_space(3))) unsigned int*)l, 16, 0, 0);
}

DI float sigm(float x) { return 1.f / (1.f + __expf(-x)); }
DI float tanh_(float x) { return 1.f - 2.f / (__expf(2.f * x) + 1.f); }

// LLC-coherent 16B load (sc0 sc1) — correctness-proven in the R12 stage role
DI u32x4 h_load16(const void* p) {  // no waitcnt: caller drains once
  u32x4 r;
  asm volatile("global_load_dwordx4 %0, %1, off sc0 sc1" : "=v"(r) : "v"(p) : "memory");
  return r;
}

// ---------------- sizes / workspace layout ----------------
// B=64 C=800 T=512 H=1024 IN=1600 4H=4096 TB=32768
// gx col layout: colp = hcol*4 + gate (gate f,i,u,o = 0..3).
// Wxt packed colp-major (gemm B); Wht packed n-major, n = gate*1024+col (lstm).
static constexpr size_t OFF_WXT  = 0;                       // bf16 [4096][1600] colp-major
static constexpr size_t OFF_WHT  = 13107200;                // bf16 [4096][1024] n-major
static constexpr size_t OFF_BSUM = OFF_WHT + 8388608;       // f32  [4096] (bx+bh, plain col)
static constexpr size_t OFF_XS   = OFF_BSUM + 16384;        // u32  [32768][800] (bf16 x,y interleaved)
static constexpr size_t OFF_GX   = OFF_XS + 104857600;      // f16  [32768][4096] (colp)
static constexpr size_t OFF_HBUF = OFF_GX + 268435456;      // u32  8 grp x 2 buf x [8][512]
static constexpr size_t OFF_BAR  = OFF_HBUF + 262144;       // u32  256 x 32-stride flags (32 KB)
static constexpr size_t WS_NEED  = OFF_BAR + 32768;

// ---------------- K1: pack gate weights, transposed, to bf16 ----------------
// perm=0: dst[n][k], n = gate*1024+col;  perm=1: dst[colp][k], colp = col*4+gate
__global__ __launch_bounds__(256) void pack_w(
    const float* __restrict__ s0, const float* __restrict__ s1,
    const float* __restrict__ s2, const float* __restrict__ s3,
    unsigned short* __restrict__ dst, int K, int perm) {
  __shared__ float tile[32][33];
  const int tx = threadIdx.x & 31, ty = threadIdx.x >> 5;
  const int kt = blockIdx.x, nt = blockIdx.y;
  const int q = (nt * 32) >> 10;
  const float* src = (q == 0) ? s0 : (q == 1) ? s1 : (q == 2) ? s2 : s3;
  const int cbase = (nt * 32) & 1023;
#pragma unroll
  for (int i = 0; i < 4; ++i) {
    int k = kt * 32 + ty + i * 8;
    tile[ty + i * 8][tx] = src[(size_t)k * 1024 + cbase + tx];
  }
  __syncthreads();
#pragma unroll
  for (int i = 0; i < 4; ++i) {
    int n = nt * 32 + ty + i * 8;
    int np = perm ? ((n & 1023) * 4 + (n >> 10)) : n;
    dst[(size_t)np * K + kt * 32 + tx] = f2bf(tile[tx][ty + i * 8]);
  }
}

// ---------------- K2: combined bias bx+bh ----------------
__global__ __launch_bounds__(256) void pack_bias(
    const float* bx0, const float* bx1, const float* bx2, const float* bx3,
    const float* bh0, const float* bh1, const float* bh2, const float* bh3,
    float* __restrict__ bsum) {
  int n = blockIdx.x * 256 + threadIdx.x;
  int q = n >> 10, j = n & 1023;
  const float* bx = (q == 0) ? bx0 : (q == 1) ? bx1 : (q == 2) ? bx2 : bx3;
  const float* bh = (q == 0) ? bh0 : (q == 1) ? bh1 : (q == 2) ? bh2 : bh3;
  bsum[n] = bx[j] + bh[j];
}

// ---------------- K3: build xs bf16 [T*B][1600] ----------------
__global__ __launch_bounds__(256) void xs_pack(
    const float* __restrict__ x, const float* __restrict__ y,
    unsigned int* __restrict__ xs32) {
  __shared__ float xt[32][33], yt[32][33];
  const int tx = threadIdx.x & 31, ty = threadIdx.x >> 5;
  const int tt = blockIdx.x, ct = blockIdx.y, b = blockIdx.z;
#pragma unroll
  for (int i = 0; i < 4; ++i) {
    int c = ct * 32 + ty + i * 8;
    int t = tt * 32 + tx;
    size_t base = ((size_t)b * 800 + c) * 512;
    xt[ty + i * 8][tx] = x[base + t];
    yt[ty + i * 8][tx] = (t == 0) ? 0.f : y[base + t - 1];
  }
  __syncthreads();
#pragma unroll
  for (int i = 0; i < 4; ++i) {
    int t = tt * 32 + ty + i * 8;
    int c = ct * 32 + tx;
    unsigned int pk = ((unsigned int)f2bf(yt[tx][ty + i * 8]) << 16) |
                      (unsigned int)f2bf(xt[tx][ty + i * 8]);
    xs32[((size_t)t * 64 + b) * 800 + c] = pk;
  }
}

// ---------------- K4: gx GEMM — 256x256 tile, BK=32, 3-slot pipeline --------
// B operand = Wxt in colp-major -> block's output cols are CONTIGUOUS in gx
// (epilogue stores sequential 32B chunks). Bias decoded per colp. Counted
// vmcnt(8) pipeline (R15/R16-proven).
__global__ __launch_bounds__(512, 2) void gemm_gx(
    const unsigned short* __restrict__ xs, const unsigned short* __restrict__ Wxtp,
    const float* __restrict__ bsum, _Float16* __restrict__ gx) {
  __shared__ __align__(16) char smem[98304];  // A: 3x16KB @0, B: 3x16KB @49152
  const int tid = threadIdx.x;
  const int w = tid >> 6, l = tid & 63;
  const int l15 = l & 15, l4 = l >> 4;
  const int wm = w >> 2, wn = w & 3;
  // XCD-aware bijective swizzle (2048 % 8 == 0)
  const int u = (blockIdx.x & 7) * 256 + (blockIdx.x >> 3);
  const int bm = u >> 4, bn = u & 15;

  const unsigned short* abase0 = xs + (size_t)(bm * 256) * 1600;
  const unsigned short* bbase0 = Wxtp + (size_t)(bn * 256) * 1600;

  const int c0 = w * 64 + l;
  const int r0 = c0 >> 2, k0 = c0 & 3;
  const int c1 = 512 + c0;
  const int r1 = c1 >> 2, k1 = c1 & 3;
  const int dst0 = w * 1024;
  const int dst1 = 8192 + w * 1024;

#define STAGE(kt2, slot)                                                        \
  {                                                                             \
    const unsigned short* ab = abase0 + (kt2) * 32;                             \
    const unsigned short* bb = bbase0 + (kt2) * 32;                             \
    char* Asl = smem + (slot) * 16384;                                          \
    char* Bsl = smem + 49152 + (slot) * 16384;                                  \
    gload_lds16(ab + (size_t)r0 * 1600 + k0 * 8, Asl + dst0);                   \
    gload_lds16(bb + (size_t)r0 * 1600 + k0 * 8, Bsl + dst0);                   \
    gload_lds16(ab + (size_t)r1 * 1600 + k1 * 8, Asl + dst1);                   \
    gload_lds16(bb + (size_t)r1 * 1600 + k1 * 8, Bsl + dst1);                   \
  }

  f32x4 acc[8][4];
#pragma unroll
  for (int i = 0; i < 8; ++i)
#pragma unroll
    for (int j = 0; j < 4; ++j) acc[i][j] = (f32x4){0.f, 0.f, 0.f, 0.f};

  STAGE(0, 0);
  STAGE(1, 1);
  STAGE(2, 2);

  int slot = 0;
  for (int t = 0; t < 50; ++t) {
    if (t < 48) {
      asm volatile("s_waitcnt vmcnt(8)" ::: "memory");
    } else {
      asm volatile("s_waitcnt vmcnt(0)" ::: "memory");
    }
    __builtin_amdgcn_s_barrier();
    const char* Asl = smem + slot * 16384;
    const char* Bsl = smem + 49152 + slot * 16384;
    short8 af[8], bf[4];
#pragma unroll
    for (int mf = 0; mf < 8; ++mf)
      af[mf] = *(const short8*)(Asl + (wm * 128 + mf * 16 + l15) * 64 + l4 * 16);
#pragma unroll
    for (int nf = 0; nf < 4; ++nf)
      bf[nf] = *(const short8*)(Bsl + (wn * 64 + nf * 16 + l15) * 64 + l4 * 16);
    __builtin_amdgcn_s_setprio(1);
#pragma unroll
    for (int mf = 0; mf < 8; ++mf)
#pragma unroll
      for (int nf = 0; nf < 4; ++nf)
        acc[mf][nf] = __builtin_amdgcn_mfma_f32_16x16x32_bf16(
            af[mf], bf[nf], acc[mf][nf], 0, 0, 0);
    __builtin_amdgcn_s_setprio(0);
    __builtin_amdgcn_s_barrier();
    asm volatile("" ::: "memory");
    if (t + 3 < 50) STAGE(t + 3, slot);
    slot = (slot == 2) ? 0 : slot + 1;
  }
#undef STAGE

  // epilogue: + bias, store f16 at contiguous colp
#pragma unroll
  for (int nf = 0; nf < 4; ++nf) {
    int colp = bn * 256 + wn * 64 + nf * 16 + l15;
    float bs = bsum[(colp & 3) * 1024 + (colp >> 2)];
#pragma unroll
    for (int mf = 0; mf < 8; ++mf) {
      int row0 = bm * 256 + wm * 128 + mf * 16 + l4 * 4;
#pragma unroll
      for (int j = 0; j < 4; ++j)
        gx[(size_t)(row0 + j) * 4096 + colp] = (_Float16)(acc[mf][nf][j] + bs);
    }
  }
}

// ---------------- K5: persistent LSTM recurrence (R15 verbatim) -------------
// 8 groups (gg=blockIdx&7) x 32 WGs (cwg), 512 thr, 96KB LDS -> 1 WG/CU.
// Wave w: ws=w&1 (h-col half), kq=w>>1 (K-slice of 256). Per step:
//   wave7 relay-polls the 32 per-WG flags (own 128B lines) -> syncA ->
//   batched cooperative 16KB h stage (2 x dwordx4 sc0sc1, one vmcnt(0),
//   2 swizzled 16B ds_writes) -> gx f16x4 loads (finalizer lanes) -> syncB ->
//   32 MFMAs (kq K-split x 4-gate A reuse) -> partials to LDS -> syncC ->
//   finalizers (kq=0) reduce + gates + h-store -> vmcnt(0) -> syncD ->
//   tid0 stores single per-WG flag (own line).
__global__ __launch_bounds__(512, 2) void lstm_seq(
    const _Float16* __restrict__ gx, const unsigned short* __restrict__ Wht,
    const float* __restrict__ subj, const float* __restrict__ Winit,
    const float* __restrict__ binit, float* __restrict__ out,
    unsigned int* __restrict__ hbuf, unsigned int* __restrict__ bar) {
  const int gg  = blockIdx.x & 7;
  const int cwg = blockIdx.x >> 3;
  const int tid = threadIdx.x;
  const int w = tid >> 6, l = tid & 63;
  const int l15 = l & 15, l4 = l >> 4;
  const int ws = w & 1, kq = w >> 1;
  const int ghc = cwg * 32 + ws * 16 + l15;  // this lane's h-col (B operand)

  __shared__ __align__(16) char smem[98304];  // 96 KB -> exclusive CU

  // Wh B-fragments (128 VGPR), resident across all 512 steps
  short8 Bf[32];
  {
    const unsigned short* wp =
        Wht + (size_t)(cwg * 32 + ws * 16 + l15) * 1024 + kq * 256 + l4 * 8;
#pragma unroll
    for (int g = 0; g < 4; ++g)
#pragma unroll
      for (int ks = 0; ks < 8; ++ks)
        Bf[g * 8 + ks] = *(const short8*)(wp + (size_t)g * 1048576 + ks * 32);
  }

  // c0 = subject_id @ W_init + b_init (finalizer lanes only)
  float c[4], hq[4][8];
  if (w < 2 && l4 < 2) {
#pragma unroll
    for (int j = 0; j < 4; ++j) {
      int b = gg * 8 + l4 * 4 + j;
      float a = binit[ghc];
      for (int k = 0; k < 87; ++k) a += subj[b * 87 + k] * Winit[k * 1024 + ghc];
      c[j] = a;
    }
  }

  unsigned int* flags = bar + gg * 1024;  // 32 WGs x 32-u32 stride (128B/line)

  // batched stage addressing: 16B chunks tid and tid+512 (1024 total = 16KB)
  const int so0 = tid * 16;
  const int so1 = (tid + 512) * 16;
  const int sw0 = so0 ^ (((so0 >> 11) & 7) << 4);
  const int sw1 = so1 ^ (((so1 >> 11) & 7) << 4);

  for (int t8 = 0; t8 < 64; ++t8) {
#pragma unroll
    for (int s = 0; s < 8; ++s) {
      const int t = t8 * 8 + s;
      const int cur = s & 1, nxt = cur ^ 1;
      // 1. poll: wave 7's 32 lanes read the 32 WG flags (distinct lines)
      if (w == 7) {
        const unsigned tgt = (unsigned)t;
        for (;;) {
          unsigned f = 0xFFFFFFFFu;
          if (l < 32)
            f = __hip_atomic_load(flags + l * 32, __ATOMIC_RELAXED,
                                  __HIP_MEMORY_SCOPE_AGENT);
          if (__all(f >= tgt)) break;
          __builtin_amdgcn_s_sleep(1);
        }
      }
      __syncthreads();  // A: h(t) visible to all
      // 2. batched cooperative stage: 2 x 16B loads, one drain, swizzled writes
      {
        const char* src = (const char*)hbuf + (size_t)(gg * 2 + cur) * 16384;
        u32x4 v0 = h_load16(src + so0);
        u32x4 v1 = h_load16(src + so1);
        asm volatile("s_waitcnt vmcnt(0)" ::: "memory");
        *(u32x4*)(smem + sw0) = v0;
        *(u32x4*)(smem + sw1) = v1;
      }
      // 3. gx loads (finalizer lanes; consumed after sync C)
      f16x4 gxq[4];
      if (w < 2 && l4 < 2) {
        const _Float16* gp =
            gx + ((size_t)(t * 64 + gg * 8 + l4 * 4)) * 4096 + ghc * 4;
#pragma unroll
        for (int j = 0; j < 4; ++j) gxq[j] = *(const f16x4*)(gp + (size_t)j * 4096);
      }
      __syncthreads();  // B: staged h readable
      // 4. MFMA: 8 A-reads, each feeds 4 gate-MFMAs
      f32x4 acc[4];
#pragma unroll
      for (int g = 0; g < 4; ++g) acc[g] = (f32x4){0.f, 0.f, 0.f, 0.f};
#pragma unroll
      for (int ks = 0; ks < 8; ++ks) {
        short8 a = *(const short8*)(
            smem + (((l15 & 7) * 2048 + kq * 512 + ks * 64 + l4 * 16) ^ ((l15 & 7) << 4)));
#pragma unroll
        for (int g = 0; g < 4; ++g)
          acc[g] = __builtin_amdgcn_mfma_f32_16x16x32_bf16(a, Bf[g * 8 + ks], acc[g], 0, 0, 0);
      }
      // 5. K-partials to LDS (waves kq>0)
      if (w >= 2) {
        char* pb = smem + 16384 + (size_t)(ws * 3 + kq - 1) * 4096;
#pragma unroll
        for (int g = 0; g < 4; ++g) *(f32x4*)(pb + g * 1024 + l * 16) = acc[g];
      }
      __syncthreads();  // C: partials readable
      // 6. reduce + gates + h-store (finalizer waves kq=0)
      if (w < 2) {
        f32x4 red[4];
#pragma unroll
        for (int g = 0; g < 4; ++g) {
          red[g] = acc[g];
#pragma unroll
          for (int kk = 0; kk < 3; ++kk)
            red[g] += *(const f32x4*)(smem + 16384 + (size_t)(ws * 3 + kk) * 4096 +
                                      g * 1024 + l * 16);
        }
        if (l4 < 2) {
#pragma unroll
          for (int j = 0; j < 4; ++j) {
            float fv = sigm(red[0][j] + (float)gxq[j][0]);
            float iv = sigm(red[1][j] + (float)gxq[j][1]);
            float uv = tanh_(red[2][j] + (float)gxq[j][2]);
            float ov = sigm(red[3][j] + (float)gxq[j][3]);
            c[j] = c[j] * fv + iv * uv;
            float hv = ov * tanh_(c[j]);
            hq[j][s] = hv;
            float hn = __shfl_xor(hv, 1);  // neighbor h-col for u32 packing
            if (!(l15 & 1)) {
              unsigned int pk = (unsigned int)f2bf(hv) | ((unsigned int)f2bf(hn) << 16);
              __hip_atomic_store(
                  hbuf + (gg * 2 + nxt) * 4096 + (l4 * 4 + j) * 512 +
                      cwg * 16 + ws * 8 + (l15 >> 1),
                  pk, __ATOMIC_RELAXED, __HIP_MEMORY_SCOPE_AGENT);
            }
          }
        }
      }
      asm volatile("s_waitcnt vmcnt(0)" ::: "memory");  // drain h-stores
      __syncthreads();  // D: both finalizer waves drained
      if (tid == 0)
        __hip_atomic_store(flags + cwg * 32, (unsigned)(t + 1),
                           __ATOMIC_RELAXED, __HIP_MEMORY_SCOPE_AGENT);
    }
    // flush 8-step h_seq window (32B chunks per lane)
    if (w < 2 && l4 < 2) {
      int tb = t8 * 8;
#pragma unroll
      for (int j = 0; j < 4; ++j) {
        f32x4 v0 = {hq[j][0], hq[j][1], hq[j][2], hq[j][3]};
        f32x4 v1 = {hq[j][4], hq[j][5], hq[j][6], hq[j][7]};
        float* op = out + (size_t)(gg * 8 + l4 * 4 + j) * 524288 + (size_t)ghc * 512 + tb;
        *(f32x4*)op = v0;
        *(f32x4*)(op + 4) = v1;
      }
    }
  }
  if (w < 2 && l4 < 2) {  // c_fin
#pragma unroll
    for (int j = 0; j < 4; ++j)
      out[33554432 + (size_t)(gg * 8 + l4 * 4 + j) * 1024 + ghc] = c[j];
  }
}

// ---------------- launch ----------------
extern "C" void kernel_launch(void* const* d_in, const int* in_sizes, int n_in,
                              void* d_out, int out_size, void* d_ws, size_t ws_size,
                              hipStream_t stream) {
  (void)in_sizes; (void)n_in; (void)out_size;
  if (ws_size < WS_NEED) return;

  const float* x     = (const float*)d_in[0];
  const float* y     = (const float*)d_in[1];
  const float* subj  = (const float*)d_in[2];
  const float* W_fx  = (const float*)d_in[3];
  const float* b_fx  = (const float*)d_in[4];
  const float* W_fh  = (const float*)d_in[5];
  const float* b_fh  = (const float*)d_in[6];
  const float* W_ix  = (const float*)d_in[7];
  const float* b_ix  = (const float*)d_in[8];
  const float* W_ih  = (const float*)d_in[9];
  const float* b_ih  = (const float*)d_in[10];
  const float* W_ux  = (const float*)d_in[11];
  const float* b_ux  = (const float*)d_in[12];
  const float* W_uh  = (const float*)d_in[13];
  const float* b_uh  = (const float*)d_in[14];
  const float* W_ox  = (const float*)d_in[15];
  const float* b_ox  = (const float*)d_in[16];
  const float* W_oh  = (const float*)d_in[17];
  const float* b_oh  = (const float*)d_in[18];
  const float* Winit = (const float*)d_in[19];
  const float* binit = (const float*)d_in[20];
  float* out = (float*)d_out;

  char* ws = (char*)d_ws;
  unsigned short* Wxt  = (unsigned short*)(ws + OFF_WXT);
  unsigned short* Wht  = (unsigned short*)(ws + OFF_WHT);
  float*          bsum = (float*)(ws + OFF_BSUM);
  unsigned int*   xs32 = (unsigned int*)(ws + OFF_XS);
  _Float16*       gx   = (_Float16*)(ws + OFF_GX);
  unsigned int*   hbuf = (unsigned int*)(ws + OFF_HBUF);
  unsigned int*   bar  = (unsigned int*)(ws + OFF_BAR);

  // deterministic per-call init: h(0)=0 in both buffers, flags=0
  hipMemsetAsync(ws + OFF_HBUF, 0, WS_NEED - OFF_HBUF, stream);

  pack_w<<<dim3(50, 128), 256, 0, stream>>>(W_fx, W_ix, W_ux, W_ox, Wxt, 1600, 1);
  pack_w<<<dim3(32, 128), 256, 0, stream>>>(W_fh, W_ih, W_uh, W_oh, Wht, 1024, 0);
  pack_bias<<<16, 256, 0, stream>>>(b_fx, b_ix, b_ux, b_ox, b_fh, b_ih, b_uh, b_oh, bsum);
  xs_pack<<<dim3(16, 25, 64), 256, 0, stream>>>(x, y, xs32);
  gemm_gx<<<2048, 512, 0, stream>>>((const unsigned short*)xs32, Wxt, bsum, gx);

  const _Float16* gxc = gx;
  const unsigned short* whtc = Wht;
  void* ka[8] = {(void*)&gxc, (void*)&whtc, (void*)&subj, (void*)&Winit,
                 (void*)&binit, (void*)&out, (void*)&hbuf, (void*)&bar};
  hipError_t e = hipLaunchCooperativeKernel((const void*)lstm_seq, dim3(256), dim3(512),
                                            ka, 0, stream);
  if (e != hipSuccess) {
    // fallback: plain launch; 256 WGs at 1 WG/CU (96KB LDS) co-resident on 256 CUs
    lstm_seq<<<256, 512, 0, stream>>>(gxc, whtc, subj, Winit, binit, out, hbuf, bar);
  }
}